// Round 17
// baseline (169.486 us; speedup 1.0000x reference)
//
#include <hip/hip_runtime.h>
#include <hip/hip_bf16.h>

// Problem: B=16,S=512 -> R=8192 rows; I=H=512; P=16.
// out[b,s,p] = cos( relu(relu(x @ W1[p]^T) @ W2[p]^T), protos[p] )
// D = W * X^T (swapped operands), 16x16x32 MFMA; W pre-packed in A-fragment order.
// 8 waves/block; wave = 64 feats x 64 tokens (4 mi x 4 nt, batched loads).
// WAVE-STAGGERED K-LOOP: wave w processes K-slices in order (kk+2w)&15, so waves
// occupy different phases (load vs MFMA) at any instant -> MFMA/LDS/L2 overlap
// across waves instead of lockstep serialization (r4: measured == exact serial sum).
#define R_TOT 8192
#define DIM   512
#define NP    16
#define EPSV  1e-6f

typedef __bf16 bf16x8 __attribute__((ext_vector_type(8)));
typedef __bf16 bf16x4 __attribute__((ext_vector_type(4)));
typedef float  f32x4  __attribute__((ext_vector_type(4)));

// X [8192][512] f32 -> bf16, rows 16B-chunk swizzled: chunk c -> c ^ (row&7)
__global__ void cvt_x_kernel(const float* __restrict__ X, unsigned short* __restrict__ Xb) {
  int t   = blockIdx.x * 256 + threadIdx.x;  // 524288 threads, 8 elems each
  int row = t >> 6;
  int c   = t & 63;
  const float4* src = (const float4*)(X + (size_t)row * DIM + c * 8);
  float4 f0 = src[0], f1 = src[1];
  bf16x8 o = {(__bf16)f0.x, (__bf16)f0.y, (__bf16)f0.z, (__bf16)f0.w,
              (__bf16)f1.x, (__bf16)f1.y, (__bf16)f1.z, (__bf16)f1.w};
  *(bf16x8*)(Xb + (size_t)row * DIM + 8 * (c ^ (row & 7))) = o;
}

// W [16][512][512] f32 -> bf16 packed in 16x16x32 A-fragment order:
// frag t = ((p*32 + mt)*16 + kk)*64 + l  holds  W[p][mt*16 + (l&15)][32*kk + 8*(l>>4) + e]
__global__ void pack_w_kernel(const float* __restrict__ W, unsigned short* __restrict__ Wp) {
  int t  = blockIdx.x * 256 + threadIdx.x;   // 524288 frags
  int l  = t & 63;
  int kk = (t >> 6) & 15;
  int mt = (t >> 10) & 31;
  int p  = t >> 15;
  int row = mt * 16 + (l & 15);
  int k0  = 32 * kk + 8 * (l >> 4);
  const float4* s = (const float4*)(W + ((size_t)p * DIM + row) * DIM + k0);
  float4 f0 = s[0], f1 = s[1];
  bf16x8 o = {(__bf16)f0.x, (__bf16)f0.y, (__bf16)f0.z, (__bf16)f0.w,
              (__bf16)f1.x, (__bf16)f1.y, (__bf16)f1.z, (__bf16)f1.w};
  *(bf16x8*)(Wp + (size_t)t * 8) = o;
}

// pn[p] = max(||protos[p]||, eps)
__global__ void proto_norm_kernel(const float* __restrict__ protos, float* __restrict__ pn) {
  int p = blockIdx.x;
  int l = threadIdx.x;   // 64
  float ss = 0.f;
  #pragma unroll
  for (int k = 0; k < DIM / 64; ++k) {
    float v = protos[p * DIM + k * 64 + l];
    ss += v * v;
  }
  #pragma unroll
  for (int m = 32; m >= 1; m >>= 1) ss += __shfl_xor(ss, m, 64);
  if (l == 0) pn[p] = fmaxf(sqrtf(ss), EPSV);
}

// One GEMM stage: acc[mi][nt] += Wfrag(4 m-tiles) x tile^T (4 n-tiles of 16 tokens)
// tile: [64 tokens][512 k] bf16, rows 1024B, 16B-chunk XOR swizzle by (token&7).
// K order staggered per wave: kk2 = (kk + koff) & 15 (sum is K-order invariant).
__device__ __forceinline__ void gemm_stage(const unsigned short* tile,
                                           const unsigned short* __restrict__ Wpk,
                                           f32x4 acc[4][4],
                                           int l, int l15, int q, int koff) {
  for (int kk = 0; kk < 16; ++kk) {
    int kk2 = (kk + koff) & 15;
    bf16x8 a[4], b[4];
    #pragma unroll
    for (int mi = 0; mi < 4; ++mi)
      a[mi] = *(const bf16x8*)(Wpk + (size_t)mi * 8192 + kk2 * 512 + l * 8);
    #pragma unroll
    for (int nt = 0; nt < 4; ++nt) {
      int token = nt * 16 + l15;
      int boff  = (64 * kk2 + 16 * q) ^ ((token & 7) << 4);
      b[nt] = *(const bf16x8*)((const char*)tile + token * 1024 + boff);
    }
    __builtin_amdgcn_s_setprio(1);
    #pragma unroll
    for (int mi = 0; mi < 4; ++mi)
      #pragma unroll
      for (int nt = 0; nt < 4; ++nt)
        acc[mi][nt] = __builtin_amdgcn_mfma_f32_16x16x32_bf16(a[mi], b[nt], acc[mi][nt], 0, 0, 0);
    __builtin_amdgcn_s_setprio(0);
  }
}

// block = (p, 64-token tile). 512 threads = 8 waves; wave w owns feats [64w, 64w+64).
__global__ __launch_bounds__(512, 4) void fused_kernel(
    const unsigned short* __restrict__ Xb,
    const unsigned short* __restrict__ W1p,
    const unsigned short* __restrict__ W2p,
    const float* __restrict__ protos,
    const float* __restrict__ pn,
    float* __restrict__ out) {
  __shared__ unsigned short tile[64 * DIM];  // 64 KB: X tile, then reused for h1
  __shared__ float red[8][64][2];            // 4 KB per-wave partial (dot, ss)

  const int raw = blockIdx.x;
  const int bid = (raw & 7) * 256 + (raw >> 3);  // XCD chunk swizzle (2048 = 8*256, bijective)
  const int p   = bid >> 7;                       // each XCD sees only 2 p values -> W fits L2
  const int r0  = (bid & 127) << 6;
  const int tid = threadIdx.x;
  const int w   = tid >> 6;
  const int l   = tid & 63;
  const int l15 = l & 15;
  const int q   = l >> 4;
  const int koff = 2 * w;                         // per-wave K-phase stagger

  // ---- load pre-swizzled X tile (two 4-deep batches: caps transient reg pressure)
  {
    const uint4* g = (const uint4*)(Xb + (size_t)r0 * DIM);
    uint4* s = (uint4*)tile;
    #pragma unroll
    for (int half = 0; half < 2; ++half) {
      uint4 v[4];
      #pragma unroll
      for (int it = 0; it < 4; ++it) v[it] = g[tid + (half * 4 + it) * 512];
      #pragma unroll
      for (int it = 0; it < 4; ++it) s[tid + (half * 4 + it) * 512] = v[it];
    }
  }
  __syncthreads();

  f32x4 acc[4][4];
  #pragma unroll
  for (int mi = 0; mi < 4; ++mi)
    #pragma unroll
    for (int nt = 0; nt < 4; ++nt) acc[mi][nt] = (f32x4){0.f, 0.f, 0.f, 0.f};

  // ---- stage 1: h1^T = relu(W1[p] @ X^T)  (wave's m-tiles: 4w .. 4w+3)
  gemm_stage(tile, W1p + ((size_t)p * 32 + 4 * w) * 8192, acc, l, l15, q, koff);

  __syncthreads();  // all X reads done before overwrite

  // write h1 back as [token][feature] bf16, same swizzle; native casts -> v_cvt_pk_bf16_f32
  #pragma unroll
  for (int mi = 0; mi < 4; ++mi)
    #pragma unroll
    for (int nt = 0; nt < 4; ++nt) {
      int token = nt * 16 + l15;
      int featb = ((4 * w + mi) * 16 + q * 4) * 2;            // byte offset, mult of 8
      bf16x4 pk = {(__bf16)fmaxf(acc[mi][nt][0], 0.f),
                   (__bf16)fmaxf(acc[mi][nt][1], 0.f),
                   (__bf16)fmaxf(acc[mi][nt][2], 0.f),
                   (__bf16)fmaxf(acc[mi][nt][3], 0.f)};
      *(bf16x4*)((char*)tile + token * 1024 + (featb ^ ((token & 7) << 4))) = pk;
    }
  __syncthreads();

  #pragma unroll
  for (int mi = 0; mi < 4; ++mi)
    #pragma unroll
    for (int nt = 0; nt < 4; ++nt) acc[mi][nt] = (f32x4){0.f, 0.f, 0.f, 0.f};

  // ---- stage 2: h2^T = relu(W2[p] @ h1^T)
  gemm_stage(tile, W2p + ((size_t)p * 32 + 4 * w) * 8192, acc, l, l15, q, koff);

  // ---- stage 3: dot with protos[p] + sum of squares, in f32
  #pragma unroll
  for (int nt = 0; nt < 4; ++nt) {
    float d = 0.f, ssq = 0.f;
    #pragma unroll
    for (int mi = 0; mi < 4; ++mi) {
      float4 pv = *(const float4*)(protos + p * DIM + (4 * w + mi) * 16 + q * 4);
      #pragma unroll
      for (int j = 0; j < 4; ++j) {
        float h = fmaxf(acc[mi][nt][j], 0.f);
        d   += h * ((const float*)&pv)[j];
        ssq += h * h;
      }
    }
    d   += __shfl_xor(d, 16, 64);
    d   += __shfl_xor(d, 32, 64);
    ssq += __shfl_xor(ssq, 16, 64);
    ssq += __shfl_xor(ssq, 32, 64);
    if (q == 0) {
      red[w][nt * 16 + l15][0] = d;
      red[w][nt * 16 + l15][1] = ssq;
    }
  }
  __syncthreads();

  if (tid < 64) {
    float d = 0.f, ssq = 0.f;
    #pragma unroll
    for (int ww = 0; ww < 8; ++ww) {
      d   += red[ww][tid][0];
      ssq += red[ww][tid][1];
    }
    float xn = fmaxf(sqrtf(ssq), EPSV);
    out[(size_t)(r0 + tid) * NP + p] = d / (xn * pn[p]);
  }
}

extern "C" void kernel_launch(void* const* d_in, const int* in_sizes, int n_in,
                              void* d_out, int out_size, void* d_ws, size_t ws_size,
                              hipStream_t stream) {
  const float* X      = (const float*)d_in[0];  // [16,512,512] = [8192][512]
  const float* W1     = (const float*)d_in[1];  // [16][512][512]
  const float* W2     = (const float*)d_in[2];  // [16][512][512]
  const float* protos = (const float*)d_in[3];  // [16][512]
  float* out = (float*)d_out;                   // [8192][16]

  unsigned short* Xb  = (unsigned short*)d_ws;                     // 8 MB
  unsigned short* W1p = Xb  + (size_t)R_TOT * DIM;                 // 8 MB (packed frags)
  unsigned short* W2p = W1p + (size_t)NP * DIM * DIM;              // 8 MB (packed frags)
  float* pn = (float*)(W2p + (size_t)NP * DIM * DIM);              // 64 B

  cvt_x_kernel<<<2048, 256, 0, stream>>>(X, Xb);
  pack_w_kernel<<<2048, 256, 0, stream>>>(W1, W1p);
  pack_w_kernel<<<2048, 256, 0, stream>>>(W2, W2p);
  proto_norm_kernel<<<NP, 64, 0, stream>>>(protos, pn);
  fused_kernel<<<2048, 512, 0, stream>>>(Xb, W1p, W2p, protos, pn, out);
}

// Round 18
// 144.973 us; speedup vs baseline: 1.1691x; 1.1691x over previous
//
#include <hip/hip_runtime.h>
#include <hip/hip_bf16.h>

// Problem: B=16,S=512 -> R=8192 rows; I=H=512; P=16.
// out[b,s,p] = cos( relu(relu(x @ W1[p]^T) @ W2[p]^T), protos[p] )
// D = W * X^T (swapped operands), 16x16x32 MFMA; W pre-packed in A-fragment order.
// 8 waves/block; wave = 64 feats x 64 tokens (4 mi x 4 nt, batched loads). r16 structure.
// Pre-pass merged into ONE kernel (cvt_x + pack W1 + pack W2 + proto norms).
#define R_TOT 8192
#define DIM   512
#define NP    16
#define EPSV  1e-6f

typedef __bf16 bf16x8 __attribute__((ext_vector_type(8)));
typedef __bf16 bf16x4 __attribute__((ext_vector_type(4)));
typedef float  f32x4  __attribute__((ext_vector_type(4)));

// ---- merged pre-pass ----------------------------------------------------
// blocks [0,2048):    X f32 -> bf16, rows 16B-chunk swizzled c -> c ^ (row&7)
// blocks [2048,4096): W1 -> bf16 packed in 16x16x32 A-frag order
// blocks [4096,6144): W2 -> same
// block  6144:        pn[p] = max(||protos[p]||, eps), 16 p x 16 lanes
__global__ void prep_kernel(const float* __restrict__ X,
                            const float* __restrict__ W1,
                            const float* __restrict__ W2,
                            const float* __restrict__ protos,
                            unsigned short* __restrict__ Xb,
                            unsigned short* __restrict__ W1p,
                            unsigned short* __restrict__ W2p,
                            float* __restrict__ pn) {
  int b = blockIdx.x;
  if (b < 2048) {
    int t   = b * 256 + threadIdx.x;          // 524288 threads, 8 elems each
    int row = t >> 6;
    int c   = t & 63;
    const float4* src = (const float4*)(X + (size_t)row * DIM + c * 8);
    float4 f0 = src[0], f1 = src[1];
    bf16x8 o = {(__bf16)f0.x, (__bf16)f0.y, (__bf16)f0.z, (__bf16)f0.w,
                (__bf16)f1.x, (__bf16)f1.y, (__bf16)f1.z, (__bf16)f1.w};
    *(bf16x8*)(Xb + (size_t)row * DIM + 8 * (c ^ (row & 7))) = o;
  } else if (b < 6144) {
    const float* W = (b < 4096) ? W1 : W2;
    unsigned short* Wp = (b < 4096) ? W1p : W2p;
    int t  = ((b - 2048) & 2047) * 256 + threadIdx.x;   // 524288 frags
    int l  = t & 63;
    int kk = (t >> 6) & 15;
    int mt = (t >> 10) & 31;
    int p  = t >> 15;
    int row = mt * 16 + (l & 15);
    int k0  = 32 * kk + 8 * (l >> 4);
    const float4* s = (const float4*)(W + ((size_t)p * DIM + row) * DIM + k0);
    float4 f0 = s[0], f1 = s[1];
    bf16x8 o = {(__bf16)f0.x, (__bf16)f0.y, (__bf16)f0.z, (__bf16)f0.w,
                (__bf16)f1.x, (__bf16)f1.y, (__bf16)f1.z, (__bf16)f1.w};
    *(bf16x8*)(Wp + (size_t)t * 8) = o;
  } else {
    int p   = threadIdx.x >> 4;               // 16 p x 16 lanes
    int l16 = threadIdx.x & 15;
    float ss = 0.f;
    #pragma unroll
    for (int k = 0; k < 32; ++k) {
      float v = protos[p * DIM + l16 * 32 + k];
      ss += v * v;
    }
    #pragma unroll
    for (int m = 8; m >= 1; m >>= 1) ss += __shfl_xor(ss, m, 16);
    if (l16 == 0) pn[p] = fmaxf(sqrtf(ss), EPSV);
  }
}

// One GEMM stage: acc[mi][nt] += Wfrag(4 m-tiles, coalesced, BATCHED) x tile^T (4 n-tiles)
// tile: [64 tokens][512 k] bf16, rows 1024B, 16B-chunk XOR swizzle by (token&7).
// Per kk: 4 A-loads + 4 B-reads issued together -> 16 MFMA (latency amortized 16x).
__device__ __forceinline__ void gemm_stage(const unsigned short* tile,
                                           const unsigned short* __restrict__ Wpk,
                                           f32x4 acc[4][4],
                                           int l, int l15, int q) {
  for (int kk = 0; kk < 16; ++kk) {
    bf16x8 a[4], b[4];
    #pragma unroll
    for (int mi = 0; mi < 4; ++mi)
      a[mi] = *(const bf16x8*)(Wpk + (size_t)mi * 8192 + kk * 512 + l * 8);
    #pragma unroll
    for (int nt = 0; nt < 4; ++nt) {
      int token = nt * 16 + l15;
      int boff  = (64 * kk + 16 * q) ^ ((token & 7) << 4);
      b[nt] = *(const bf16x8*)((const char*)tile + token * 1024 + boff);
    }
    __builtin_amdgcn_s_setprio(1);
    #pragma unroll
    for (int mi = 0; mi < 4; ++mi)
      #pragma unroll
      for (int nt = 0; nt < 4; ++nt)
        acc[mi][nt] = __builtin_amdgcn_mfma_f32_16x16x32_bf16(a[mi], b[nt], acc[mi][nt], 0, 0, 0);
    __builtin_amdgcn_s_setprio(0);
  }
}

// block = (p, 64-token tile). 512 threads = 8 waves; wave w owns feats [64w, 64w+64).
__global__ __launch_bounds__(512, 4) void fused_kernel(
    const unsigned short* __restrict__ Xb,
    const unsigned short* __restrict__ W1p,
    const unsigned short* __restrict__ W2p,
    const float* __restrict__ protos,
    const float* __restrict__ pn,
    float* __restrict__ out) {
  __shared__ unsigned short tile[64 * DIM];  // 64 KB: X tile, then reused for h1
  __shared__ float red[8][64][2];            // 4 KB per-wave partial (dot, ss)

  const int raw = blockIdx.x;
  const int bid = (raw & 7) * 256 + (raw >> 3);  // XCD chunk swizzle (2048 = 8*256, bijective)
  const int p   = bid >> 7;                       // each XCD sees only 2 p values -> W fits L2
  const int r0  = (bid & 127) << 6;
  const int tid = threadIdx.x;
  const int w   = tid >> 6;
  const int l   = tid & 63;
  const int l15 = l & 15;
  const int q   = l >> 4;

  // ---- load pre-swizzled X tile (two 4-deep batches: caps transient reg pressure)
  {
    const uint4* g = (const uint4*)(Xb + (size_t)r0 * DIM);
    uint4* s = (uint4*)tile;
    #pragma unroll
    for (int half = 0; half < 2; ++half) {
      uint4 v[4];
      #pragma unroll
      for (int it = 0; it < 4; ++it) v[it] = g[tid + (half * 4 + it) * 512];
      #pragma unroll
      for (int it = 0; it < 4; ++it) s[tid + (half * 4 + it) * 512] = v[it];
    }
  }
  __syncthreads();

  f32x4 acc[4][4];
  #pragma unroll
  for (int mi = 0; mi < 4; ++mi)
    #pragma unroll
    for (int nt = 0; nt < 4; ++nt) acc[mi][nt] = (f32x4){0.f, 0.f, 0.f, 0.f};

  // ---- stage 1: h1^T = relu(W1[p] @ X^T)  (wave's m-tiles: 4w .. 4w+3)
  gemm_stage(tile, W1p + ((size_t)p * 32 + 4 * w) * 8192, acc, l, l15, q);

  __syncthreads();  // all X reads done before overwrite

  // write h1 back as [token][feature] bf16, same swizzle; native casts -> v_cvt_pk_bf16_f32
  #pragma unroll
  for (int mi = 0; mi < 4; ++mi)
    #pragma unroll
    for (int nt = 0; nt < 4; ++nt) {
      int token = nt * 16 + l15;
      int featb = ((4 * w + mi) * 16 + q * 4) * 2;            // byte offset, mult of 8
      bf16x4 pk = {(__bf16)fmaxf(acc[mi][nt][0], 0.f),
                   (__bf16)fmaxf(acc[mi][nt][1], 0.f),
                   (__bf16)fmaxf(acc[mi][nt][2], 0.f),
                   (__bf16)fmaxf(acc[mi][nt][3], 0.f)};
      *(bf16x4*)((char*)tile + token * 1024 + (featb ^ ((token & 7) << 4))) = pk;
    }
  __syncthreads();

  #pragma unroll
  for (int mi = 0; mi < 4; ++mi)
    #pragma unroll
    for (int nt = 0; nt < 4; ++nt) acc[mi][nt] = (f32x4){0.f, 0.f, 0.f, 0.f};

  // ---- stage 2: h2^T = relu(W2[p] @ h1^T)
  gemm_stage(tile, W2p + ((size_t)p * 32 + 4 * w) * 8192, acc, l, l15, q);

  // ---- stage 3: dot with protos[p] + sum of squares, in f32
  #pragma unroll
  for (int nt = 0; nt < 4; ++nt) {
    float d = 0.f, ssq = 0.f;
    #pragma unroll
    for (int mi = 0; mi < 4; ++mi) {
      float4 pv = *(const float4*)(protos + p * DIM + (4 * w + mi) * 16 + q * 4);
      #pragma unroll
      for (int j = 0; j < 4; ++j) {
        float h = fmaxf(acc[mi][nt][j], 0.f);
        d   += h * ((const float*)&pv)[j];
        ssq += h * h;
      }
    }
    d   += __shfl_xor(d, 16, 64);
    d   += __shfl_xor(d, 32, 64);
    ssq += __shfl_xor(ssq, 16, 64);
    ssq += __shfl_xor(ssq, 32, 64);
    if (q == 0) {
      red[w][nt * 16 + l15][0] = d;
      red[w][nt * 16 + l15][1] = ssq;
    }
  }
  __syncthreads();

  if (tid < 64) {
    float d = 0.f, ssq = 0.f;
    #pragma unroll
    for (int ww = 0; ww < 8; ++ww) {
      d   += red[ww][tid][0];
      ssq += red[ww][tid][1];
    }
    float xn = fmaxf(sqrtf(ssq), EPSV);
    out[(size_t)(r0 + tid) * NP + p] = d / (xn * pn[p]);
  }
}

extern "C" void kernel_launch(void* const* d_in, const int* in_sizes, int n_in,
                              void* d_out, int out_size, void* d_ws, size_t ws_size,
                              hipStream_t stream) {
  const float* X      = (const float*)d_in[0];  // [16,512,512] = [8192][512]
  const float* W1     = (const float*)d_in[1];  // [16][512][512]
  const float* W2     = (const float*)d_in[2];  // [16][512][512]
  const float* protos = (const float*)d_in[3];  // [16][512]
  float* out = (float*)d_out;                   // [8192][16]

  unsigned short* Xb  = (unsigned short*)d_ws;                     // 8 MB
  unsigned short* W1p = Xb  + (size_t)R_TOT * DIM;                 // 8 MB (packed frags)
  unsigned short* W2p = W1p + (size_t)NP * DIM * DIM;              // 8 MB (packed frags)
  float* pn = (float*)(W2p + (size_t)NP * DIM * DIM);              // 64 B

  prep_kernel<<<6145, 256, 0, stream>>>(X, W1, W2, protos, Xb, W1p, W2p, pn);
  fused_kernel<<<2048, 512, 0, stream>>>(Xb, W1p, W2p, protos, pn, out);
}